// Round 1
// baseline (77.901 us; speedup 1.0000x reference)
//
#include <hip/hip_runtime.h>
#include <math.h>

#define LN_EPS 1e-5f

// Problem constants (fixed by setup_inputs): N=10, K=5, Q=5, H=256, Qtot=N*Q=50
constexpr int Nn  = 10;
constexpr int Kk  = 5;
constexpr int Hh  = 256;
constexpr int QT  = 50;   // Qtot
constexpr int NP1 = 11;   // N+1

// ---------- LayerNorm helpers ----------
// 64-lane-per-row layout: lane holds h = 4*lane .. 4*lane+3
__device__ __forceinline__ void ln_row64(const float* __restrict__ row,
                                         const float* __restrict__ g,
                                         const float* __restrict__ bt,
                                         int lane, float y[4]) {
    const float4 x = *reinterpret_cast<const float4*>(row + lane * 4);
    float s  = x.x + x.y + x.z + x.w;
    float ss = x.x * x.x + x.y * x.y + x.z * x.z + x.w * x.w;
#pragma unroll
    for (int m = 1; m < 64; m <<= 1) {
        s  += __shfl_xor(s, m);
        ss += __shfl_xor(ss, m);
    }
    const float mu   = s * (1.0f / (float)Hh);
    const float var  = ss * (1.0f / (float)Hh) - mu * mu;
    const float rstd = rsqrtf(var + LN_EPS);
    const int h = lane * 4;
    y[0] = (x.x - mu) * rstd * g[h + 0] + bt[h + 0];
    y[1] = (x.y - mu) * rstd * g[h + 1] + bt[h + 1];
    y[2] = (x.z - mu) * rstd * g[h + 2] + bt[h + 2];
    y[3] = (x.w - mu) * rstd * g[h + 3] + bt[h + 3];
}

// 16-lane-group layout: sub-lane holds h = 16*sub .. 16*sub+15 (4 rows per wave)
__device__ __forceinline__ void ln_row16(const float* __restrict__ row,
                                         const float* __restrict__ g,
                                         const float* __restrict__ bt,
                                         int sub, float y[16]) {
    const float* p = row + sub * 16;
    float s = 0.f, ss = 0.f;
#pragma unroll
    for (int c = 0; c < 4; ++c) {
        const float4 x = *reinterpret_cast<const float4*>(p + c * 4);
        y[c * 4 + 0] = x.x; y[c * 4 + 1] = x.y;
        y[c * 4 + 2] = x.z; y[c * 4 + 3] = x.w;
        s  += x.x + x.y + x.z + x.w;
        ss += x.x * x.x + x.y * x.y + x.z * x.z + x.w * x.w;
    }
#pragma unroll
    for (int m = 1; m < 16; m <<= 1) {
        s  += __shfl_xor(s, m);
        ss += __shfl_xor(ss, m);
    }
    const float mu   = s * (1.0f / (float)Hh);
    const float rstd = rsqrtf(ss * (1.0f / (float)Hh) - mu * mu + LN_EPS);
    const int hb = sub * 16;
#pragma unroll
    for (int j = 0; j < 16; ++j)
        y[j] = (y[j] - mu) * rstd * g[hb + j] + bt[hb + j];
}

__device__ __forceinline__ float grp16_reduce_add(float v) {
#pragma unroll
    for (int m = 1; m < 16; m <<= 1) v += __shfl_xor(v, m);
    return v;
}

__global__ __launch_bounds__(256) void proto_rectify_kernel(
    const float* __restrict__ support, const float* __restrict__ query,
    const float* __restrict__ gamma,   const float* __restrict__ beta,
    float* __restrict__ out, int B)
{
    const int b    = blockIdx.x;
    const int tid  = threadIdx.x;
    const int lane = tid & 63;
    const int wave = tid >> 6;
    const int grp  = (tid >> 4) & 3;  // 16-lane group within wave
    const int sub  = tid & 15;        // lane within group

    __shared__ float g_s[Hh], bt_s[Hh];
    __shared__ float M_s[Nn * Hh];
    __shared__ float proto_s[Nn * Hh];
    __shared__ float score_sup[Nn * Kk];
    __shared__ float w_sup[Nn * Kk];
    __shared__ float wq_s[QT];
    __shared__ int   cq_s[QT];
    __shared__ int   cnt_s[Nn];

    // Preload gamma/beta; zero counts.
    g_s[tid]  = gamma[tid];
    bt_s[tid] = beta[tid];
    if (tid < Nn) cnt_s[tid] = 0;
    __syncthreads();

    const float* supB = support + (size_t)b * (Nn * Kk * Hh);
    const float* qryB = query   + (size_t)b * (QT * Hh);

    // ---------- Phase A: LN support, prototypes M, support scores ----------
    // wave-per-proto; all 5 LN'd rows held in registers
    for (int n = wave; n < Nn; n += 4) {
        float y[Kk][4];
#pragma unroll
        for (int k = 0; k < Kk; ++k)
            ln_row64(supB + (n * Kk + k) * Hh, g_s, bt_s, lane, y[k]);

        float Mv[4];
#pragma unroll
        for (int i = 0; i < 4; ++i) {
            Mv[i] = (y[0][i] + y[1][i] + y[2][i] + y[3][i] + y[4][i]) / 5.0f;
            M_s[n * Hh + lane * 4 + i] = Mv[i];
        }
#pragma unroll
        for (int k = 0; k < Kk; ++k) {
            float p = y[k][0] * Mv[0] + y[k][1] * Mv[1] +
                      y[k][2] * Mv[2] + y[k][3] * Mv[3];
#pragma unroll
            for (int m = 1; m < 64; m <<= 1) p += __shfl_xor(p, m);
            if (lane == 0) score_sup[n * Kk + k] = p;
        }
    }
    __syncthreads();

    // ---------- Phase B: softmax over N per support slot k (stable) ----------
    if (tid < Kk) {
        const int k = tid;
        float mx = -INFINITY;
#pragma unroll
        for (int n = 0; n < Nn; ++n) mx = fmaxf(mx, score_sup[n * Kk + k]);
        float e[Nn];
        float den = 0.f;
#pragma unroll
        for (int n = 0; n < Nn; ++n) { e[n] = expf(score_sup[n * Kk + k] - mx); den += e[n]; }
#pragma unroll
        for (int n = 0; n < Nn; ++n) w_sup[n * Kk + k] = e[n] / den;
    }
    __syncthreads();

    // ---------- Phase C: queries -> nearest proto Cq, query weight wq ----------
    // 16-lane groups: 4 queries per wave per iteration
    for (int it = 0; it < 4; ++it) {
        const int q = it * 16 + wave * 4 + grp;
        if (q < QT) {
            float y16[16];
            ln_row16(qryB + q * Hh, g_s, bt_s, sub, y16);
            const int hb = sub * 16;
            float bestd = INFINITY; int bestn = 0;
#pragma unroll
            for (int n = 0; n < Nn; ++n) {
                float p = 0.f;
#pragma unroll
                for (int j = 0; j < 16; ++j) {
                    const float d = y16[j] - M_s[n * Hh + hb + j];
                    p = fmaf(d, d, p);
                }
                p = grp16_reduce_add(p);
                if (p < bestd) { bestd = p; bestn = n; }  // first-index tie-break
            }
            float sc = 0.f;
#pragma unroll
            for (int j = 0; j < 16; ++j) sc = fmaf(y16[j], M_s[bestn * Hh + hb + j], sc);
            sc = grp16_reduce_add(sc);
            if (sub == 0) {
                // softmax over N at this slot: {sc} ∪ {0}×(N-1), max-subtracted
                const float mx = fmaxf(sc, 0.f);
                const float e  = expf(sc - mx);
                const float den = e + (float)(Nn - 1) * expf(-mx);
                wq_s[q] = e / den;
                cq_s[q] = bestn;
                atomicAdd(&cnt_s[bestn], 1);
            }
        }
    }
    __syncthreads();

    // ---------- Phase E: weighted prototype accumulation ----------
    for (int n = wave; n < Nn; n += 4) {
        float acc[4] = {0.f, 0.f, 0.f, 0.f};
#pragma unroll
        for (int k = 0; k < Kk; ++k) {
            float y[4];
            ln_row64(supB + (n * Kk + k) * Hh, g_s, bt_s, lane, y);
            const float w = w_sup[n * Kk + k];
#pragma unroll
            for (int i = 0; i < 4; ++i) acc[i] = fmaf(w, y[i], acc[i]);
        }
        for (int q = 0; q < QT; ++q) {
            if (cq_s[q] == n) {   // wave-uniform branch
                float y[4];
                ln_row64(qryB + q * Hh, g_s, bt_s, lane, y);
                const float w = wq_s[q];
#pragma unroll
                for (int i = 0; i < 4; ++i) acc[i] = fmaf(w, y[i], acc[i]);
            }
        }
        const float size = (float)(Kk + cnt_s[n]);
#pragma unroll
        for (int i = 0; i < 4; ++i)
            proto_s[n * Hh + lane * 4 + i] = acc[i] / size;
    }
    __syncthreads();

    // ---------- Phase F: logits + pred ----------
    float* predOut = out + (size_t)B * QT * NP1;
    for (int it = 0; it < 4; ++it) {
        const int q = it * 16 + wave * 4 + grp;
        if (q < QT) {
            float y16[16];
            ln_row16(qryB + q * Hh, g_s, bt_s, sub, y16);
            const int hb = sub * 16;
            float d[Nn];
            float maxd = -INFINITY, bestd = INFINITY;
            int bestn = 0;
#pragma unroll
            for (int n = 0; n < Nn; ++n) {
                float p = 0.f;
#pragma unroll
                for (int j = 0; j < 16; ++j) {
                    const float dd = y16[j] - proto_s[n * Hh + hb + j];
                    p = fmaf(dd, dd, p);
                }
                p = grp16_reduce_add(p);
                d[n] = p;
                maxd = fmaxf(maxd, p);
                if (p < bestd) { bestd = p; bestn = n; }
            }
            if (sub == 0) {
                float* o = out + ((size_t)b * QT + q) * NP1;
#pragma unroll
                for (int n = 0; n < Nn; ++n) o[n] = -d[n];
                o[Nn] = -maxd - 1.0f;           // min(logits) - 1
                predOut[(size_t)b * QT + q] = (float)bestn;
            }
        }
    }
}

extern "C" void kernel_launch(void* const* d_in, const int* in_sizes, int n_in,
                              void* d_out, int out_size, void* d_ws, size_t ws_size,
                              hipStream_t stream) {
    const float* support = (const float*)d_in[0];
    const float* query   = (const float*)d_in[1];
    const float* gamma   = (const float*)d_in[2];
    const float* beta    = (const float*)d_in[3];
    float* out = (float*)d_out;

    const int B = in_sizes[0] / (Nn * Kk * Hh);   // 512
    proto_rectify_kernel<<<B, 256, 0, stream>>>(support, query, gamma, beta, out, B);
}